// Round 15
// baseline (1206.807 us; speedup 1.0000x reference)
//
#include <hip/hip_runtime.h>
#include <hip/hip_bf16.h>
#include <hip/hip_cooperative_groups.h>
#include <math.h>

#define NN 15000      // nodes
#define NE 60000      // edges
#define DIN 74
#define DEIN 12
#define DD 64         // node feat dim
#define EH 128        // edge hidden
#define NG 8192       // EH*DD
#define NSTEPS 6
#define NRB 235       // ceil(NN/64)  (tail blocks / BN partials)
#define KAB 384       // GRU split-A width: [m_hi,h_hi,m_lo,h_lo,m_hi,h_hi]
#define NTMAX 18752   // >= NN + NE/16 tiles (deg split into <=16-edge tiles)
#define NFB 586       // ceil(18750/32) fused blocks

namespace cg = cooperative_groups;

typedef unsigned short ushort_t;
typedef __attribute__((ext_vector_type(8))) short short8v;
typedef __attribute__((ext_vector_type(4))) float float4v;

__device__ __forceinline__ float bsf(unsigned short u){
  union { unsigned int i; float f; } v; v.i = ((unsigned int)u) << 16; return v.f;
}
__device__ __forceinline__ unsigned short fsb(float f){
  union { float f; unsigned int i; } v; v.f = f;
  unsigned int x = v.i;
  return (unsigned short)((x + 0x7FFFu + ((x >> 16) & 1u)) >> 16);
}
// packed RNE f32x2 -> bf16x2 (same rounding as fsb, HW v_cvt_pk_bf16_f32)
__device__ __forceinline__ unsigned int pkbf(float a, float b){
  __hip_bfloat162 r = __float22bfloat162_rn(make_float2(a, b));
  union { __hip_bfloat162 h; unsigned int u; } v; v.h = r; return v.u;
}

// ---------- dtype sniff
__global__ void k_sniff(const ushort_t* __restrict__ nf16,
                        const int* __restrict__ dsti, int* __restrict__ flags){
  __shared__ int cnt[2];
  int t = threadIdx.x;
  if (t < 2) cnt[t] = 0;
  __syncthreads();
  int bad = 0;
  for (int i = t; i < 1024; i += 256){
    unsigned short u = nf16[2*i];
    int e = (u >> 7) & 0xFF;
    if (e < 96 || e > 159) bad++;
  }
  if (bad) atomicAdd(&cnt[0], bad);
  if (t < 256 && dsti[2*t+1] == 0) atomicAdd(&cnt[1], 1);
  __syncthreads();
  if (t == 0){
    flags[0] = (cnt[0] > 300) ? 1 : 0;
    flags[1] = (cnt[1] > 250) ? 1 : 0;
  }
}

// ---------- batched canonicalization: 15 tensors in one dispatch
struct CanonArgs {
  const void* in[15];
  float* out[15];
  int n[15];
};
__global__ void k_canon_all(CanonArgs a, const int* __restrict__ flags){
  int j = blockIdx.y;
  int n = a.n[j];
  int fp32 = flags[0];
  const void* in = a.in[j];
  float* out = a.out[j];
  for (int i = blockIdx.x*256 + threadIdx.x; i < n; i += gridDim.x*256){
    if (fp32) out[i] = ((const float*)in)[i];
    else      out[i] = bsf(((const ushort_t*)in)[i]);
  }
}
// both index arrays in one dispatch (blockIdx.y = which)
__global__ void k_canoni2(const void* __restrict__ in0, const void* __restrict__ in1,
                          int* __restrict__ out0, int* __restrict__ out1,
                          const int* __restrict__ flags){
  int i = blockIdx.x*256 + threadIdx.x;
  if (i >= NE) return;
  const void* in = blockIdx.y ? in1 : in0;
  int* out = blockIdx.y ? out1 : out0;
  long long v = flags[1] ? ((const long long*)in)[i]
                         : (long long)((const int*)in)[i];
  int vi = (int)v;
  if (vi < 0) vi = 0;
  if (vi >= NN) vi = NN-1;
  out[i] = vi;
}

// ---------- one-time: h0 = relu(nf @ W_proj + b_proj) -> fp32 hid + ab h-parts
__global__ void k_proj(const float* __restrict__ nf, const float* __restrict__ Wp,
                       const float* __restrict__ bp, float* __restrict__ hid,
                       ushort_t* __restrict__ ab){
  __shared__ float nfl[4][DIN];
  int t = threadIdx.x, blk = blockIdx.x;
  for (int idx = t; idx < 4*DIN; idx += 256){
    int vl = idx / DIN, i = idx - vl*DIN;
    nfl[vl][i] = nf[(size_t)(blk*4+vl)*DIN + i];
  }
  __syncthreads();
  int vl = t >> 6, o = t & 63;
  int v = blk*4 + vl;
  float acc = bp[o];
  for (int i = 0; i < DIN; ++i) acc += nfl[vl][i] * Wp[i*DD + o];
  float r = fmaxf(acc, 0.f);
  hid[(size_t)v*DD + o] = r;
  ushort_t hh = fsb(r);
  float hl = r - bsf(hh);
  ab[(size_t)v*KAB + 64 + o]  = hh;        // h_hi
  ab[(size_t)v*KAB + 192 + o] = fsb(hl);   // h_lo
  ab[(size_t)v*KAB + 320 + o] = hh;        // h_hi copy (pairs W_lo)
}

// ---------- one-time: t = relu(ef @ W_e1 + b_e1), split bf16 hi/lo
__global__ void k_emlp(const float* __restrict__ ef, const float* __restrict__ W1,
                       const float* __restrict__ b1, ushort_t* __restrict__ thi,
                       ushort_t* __restrict__ tlo){
  __shared__ float efl[2][DEIN];
  int t = threadIdx.x, blk = blockIdx.x;
  if (t < 2*DEIN){
    int el = t / DEIN, i = t - el*DEIN;
    efl[el][i] = ef[(size_t)(blk*2+el)*DEIN + i];
  }
  __syncthreads();
  int el = t >> 7, c = t & 127;
  float acc = b1[c];
  for (int i = 0; i < DEIN; ++i) acc += efl[el][i] * W1[i*EH + c];
  float tv = fmaxf(acc, 0.f);
  ushort_t hiv = fsb(tv);
  size_t off = (size_t)(blk*2+el)*EH + c;
  thi[off] = hiv;
  tlo[off] = fsb(tv - bsf(hiv));
}
__global__ void k_zpad(ushort_t* __restrict__ thi, ushort_t* __restrict__ tlo){
  int t = threadIdx.x;   // 128
  thi[(size_t)NE*EH + t] = 0;
  tlo[(size_t)NE*EH + t] = 0;
}

// ---------- one-time: w2q rows ordered [kq(4)][o(64)][k_local(32)] x i(64)
// plus w2b[o][i] bias fold rows
__global__ void k_w2q(const float* __restrict__ W2, const float* __restrict__ b2,
                      ushort_t* __restrict__ w2q, ushort_t* __restrict__ w2b){
  int idx = blockIdx.x*256 + threadIdx.x;
  if (idx < NG*DD){
    int n = idx >> 6, i = idx & 63;
    int kq = n >> 11, rem = n & 2047;
    int o = rem >> 5, kl = rem & 31;
    int kg = kq*32 + kl;
    w2q[idx] = fsb(W2[(size_t)kg*4096 + i*64 + o]);
  } else if (idx < NG*DD + DD*DD){
    int r = idx - NG*DD;
    int o = r >> 6, i = r & 63;
    w2b[r] = fsb(b2[i*64 + o]);
  }
}

// ---------- one-time: GRU split weight matrix wg[c][k], c in [0,256), k in [0,384)
__global__ void k_wgru(const float* __restrict__ Wih, const float* __restrict__ Whh,
                       ushort_t* __restrict__ wg){
  int pos = blockIdx.x*256 + threadIdx.x;
  if (pos >= 256*KAB) return;
  int c = pos / KAB, k = pos - c*KAB;
  int kb = k >> 6, i = k & 63;
  int g = c >> 6, o = c & 63;
  float w = 0.f;
  if ((kb & 1) == 0){          // m-side: Wih
    if (g == 0)      w = Wih[(size_t)(o)*64 + i];
    else if (g == 1) w = Wih[(size_t)(64+o)*64 + i];
    else if (g == 2) w = Wih[(size_t)(128+o)*64 + i];
  } else {                     // h-side: Whh
    if (g == 0)      w = Whh[(size_t)(o)*64 + i];
    else if (g == 1) w = Whh[(size_t)(64+o)*64 + i];
    else if (g == 3) w = Whh[(size_t)(128+o)*64 + i];
  }
  ushort_t hi = fsb(w);
  wg[pos] = (kb >= 4) ? fsb(w - bsf(hi)) : hi;
}

// ---------- CSR build (both directions, merged dispatches)
__global__ void k_zero(int* __restrict__ p, int n){
  int i = blockIdx.x*256 + threadIdx.x;
  if (i < n) p[i] = 0;
}
__global__ void k_deg2(const int* __restrict__ a0, const int* __restrict__ a1,
                       int* __restrict__ d0, int* __restrict__ d1){
  int e = blockIdx.x*256 + threadIdx.x;
  if (e < NE){
    if (blockIdx.y == 0) atomicAdd(&d0[a0[e]], 1);
    else                 atomicAdd(&d1[a1[e]], 1);
  }
}
__global__ void k_scan2(const int* __restrict__ degA, int* __restrict__ rowpA,
                        float* __restrict__ invdA,
                        const int* __restrict__ degB, int* __restrict__ rowpB,
                        float* __restrict__ invdB){
  const int* deg = blockIdx.x ? degB : degA;
  int* rowp      = blockIdx.x ? rowpB : rowpA;
  float* invd    = blockIdx.x ? invdB : invdA;
  __shared__ int ssum[256];
  int t = threadIdx.x;
  const int STRIP = (NN + 255) / 256;
  int lo = t*STRIP, hi = (lo + STRIP < NN) ? lo + STRIP : NN;
  int s = 0;
  for (int i = lo; i < hi; ++i) s += deg[i];
  ssum[t] = s;
  __syncthreads();
  if (t == 0){
    int acc = 0;
    for (int i = 0; i < 256; ++i){ int v = ssum[i]; ssum[i] = acc; acc += v; }
  }
  __syncthreads();
  int acc = ssum[t];
  for (int i = lo; i < hi; ++i){
    rowp[i] = acc;
    int d = deg[i];
    invd[i] = (d > 0) ? 1.0f/(float)d : 0.0f;
    acc += d;
  }
  if (t == 255) rowp[NN] = acc;
}
__global__ void k_scatter2(const int* __restrict__ dstc, const int* __restrict__ rowpD,
                           int* __restrict__ curD, int* __restrict__ eidxD,
                           int* __restrict__ epos,
                           const int* __restrict__ srcc, const int* __restrict__ rowpS,
                           int* __restrict__ curS, int* __restrict__ eidxS){
  int e = blockIdx.x*256 + threadIdx.x;
  if (e >= NE) return;
  if (blockIdx.y == 0){
    int d = dstc[e];
    int pos = atomicAdd(&curD[d], 1);
    int slot = rowpD[d] + pos;
    eidxD[slot] = e;
    epos[e] = slot;
  } else {
    int d = srcc[e];
    int pos = atomicAdd(&curS[d], 1);
    eidxS[rowpS[d] + pos] = e;
  }
}

// ---------- one-time: split src CSR into tiles of <=16 edges
__global__ void k_tiles(const int* __restrict__ rowp, int* __restrict__ tnode,
                        int* __restrict__ tbase, int* __restrict__ tcnt,
                        int* __restrict__ ntb){
  __shared__ int ss[256];
  int t = threadIdx.x;
  const int STRIP = (NN + 255) / 256;
  int lo = t*STRIP, hi = lo + STRIP; if (hi > NN) hi = NN;
  int c = 0;
  for (int i = lo; i < hi; ++i){
    int deg = rowp[i+1] - rowp[i];
    c += (deg + 15) >> 4;
  }
  ss[t] = c;
  __syncthreads();
  if (t == 0){
    int a = 0;
    for (int i = 0; i < 256; ++i){ int v = ss[i]; ss[i] = a; a += v; }
    ntb[0] = a;
  }
  __syncthreads();
  int pos = ss[t];
  for (int i = lo; i < hi; ++i){
    int b = rowp[i], deg = rowp[i+1] - b;
    for (int r = 0; r < deg; r += 16){
      tnode[pos] = i; tbase[pos] = b + r;
      int c2 = deg - r; tcnt[pos] = (c2 > 16) ? 16 : c2;
      ++pos;
    }
  }
}

// ---------- FUSED per step, all-MFMA, ATOMIC-FREE (proven form):
// block = 32 src tiles. Per (oh, kq) chunk:
//   GEMM1: Gl[m][k32][o32] = w2q-chunk @ h (v_cvt_pk pack, XOR-swizzled 8B wr)
//   GEMM2: acc[j][ot] += T @ Gl (B-frags)
// flush per o-half: coalesced stores of msg at DST-CSR slot epos[e].
__global__ __launch_bounds__(512,4) void k_fused7(
    const ushort_t* __restrict__ ab, const ushort_t* __restrict__ w2q,
    const ushort_t* __restrict__ w2b, const ushort_t* __restrict__ thi,
    const ushort_t* __restrict__ tlo,
    const int* __restrict__ tnode, const int* __restrict__ tbase,
    const int* __restrict__ tcnt, const int* __restrict__ ntb,
    const int* __restrict__ eidx, const int* __restrict__ epos,
    float* __restrict__ msg){
  __shared__ __align__(16) ushort_t Gl[32768];   // [m32][q8:4][o32][8] = 64 KB
  __shared__ float bhl[32*66];                   // 8.25 KB bias tile (pad 66)
  __shared__ int nodl[32], cntl[32], basel[32];
  __shared__ int eidl[32][16];
  __shared__ int posl[32][16];

  int tid = threadIdx.x;
  int nt = ntb[0];
  int T0 = blockIdx.x * 32;
  if (T0 >= nt) return;
  int wv = tid >> 6, lane = tid & 63;
  int lr = lane & 15, quad = lane >> 4;

  if (tid < 32){
    int gt = T0 + tid;
    int node = 0, base = 0, cnt = 0;
    if (gt < nt){ node = tnode[gt]; base = tbase[gt]; cnt = tcnt[gt]; }
    nodl[tid] = node; basel[tid] = base; cntl[tid] = cnt;
  }
  __syncthreads();
  {
    int j = tid >> 4, sl = tid & 15;
    int eid = NE, ps = 0;
    if (sl < cntl[j]){
      eid = eidx[basel[j] + sl];
      ps = epos[eid];
    }
    eidl[j][sl] = eid;
    posl[j][sl] = ps;
  }
  // h_hi B-fragments for both m-halves (col = lane&15 = m, k=i at quad*8)
  short8v hf0k0, hf0k1, hf1k0, hf1k1;
  {
    int n0 = nodl[lr], n1 = nodl[16 + lr];
    hf0k0 = *(const short8v*)(ab + (size_t)n0*KAB + 64 + quad*8);
    hf0k1 = *(const short8v*)(ab + (size_t)n0*KAB + 96 + quad*8);
    hf1k0 = *(const short8v*)(ab + (size_t)n1*KAB + 64 + quad*8);
    hf1k1 = *(const short8v*)(ab + (size_t)n1*KAB + 96 + quad*8);
  }
  // bias tile bh[m][o] = h @ b2 via MFMA (A = w2b rows o, B = h)
  {
    int ot = wv & 3, mh = wv >> 2;
    float4v ba = (float4v){0.f,0.f,0.f,0.f};
    short8v a0 = *(const short8v*)(w2b + (size_t)(ot*16 + lr)*DD + quad*8);
    short8v a1 = *(const short8v*)(w2b + (size_t)(ot*16 + lr)*DD + 32 + quad*8);
    ba = __builtin_amdgcn_mfma_f32_16x16x32_bf16(a0, mh ? hf1k0 : hf0k0, ba, 0,0,0);
    ba = __builtin_amdgcn_mfma_f32_16x16x32_bf16(a1, mh ? hf1k1 : hf0k1, ba, 0,0,0);
    #pragma unroll
    for (int reg = 0; reg < 4; ++reg)
      bhl[(mh*16 + lr)*66 + ot*16 + quad*4 + reg] = ba[reg];
  }

  int j0 = wv*4;                         // this wave's 4 src tiles
  for (int oh = 0; oh < 2; ++oh){
    float4v acc[4][2];
    #pragma unroll
    for (int j = 0; j < 4; ++j)
      #pragma unroll
      for (int ot = 0; ot < 2; ++ot)
        acc[j][ot] = (float4v){0.f,0.f,0.f,0.f};
    for (int kq = 0; kq < 4; ++kq){
      __syncthreads();                   // Gl consumable -> writable
      // GEMM1: this wave's 8 n-tiles (128 consecutive w2q rows)
      #pragma unroll 4
      for (int it = 0; it < 8; ++it){
        int tile = wv*8 + it;
        int nrow = kq*2048 + oh*1024 + tile*16 + lr;
        const ushort_t* arow = w2q + (size_t)nrow*DD;
        short8v a0 = *(const short8v*)(arow + quad*8);
        short8v a1 = *(const short8v*)(arow + 32 + quad*8);
        int ol = tile >> 1;
        int klb = ((tile & 1) << 4) + quad*4;
        int q8 = klb >> 3, jj = klb & 7;
        #pragma unroll
        for (int mh = 0; mh < 2; ++mh){
          float4v g = (float4v){0.f,0.f,0.f,0.f};
          g = __builtin_amdgcn_mfma_f32_16x16x32_bf16(a0, mh ? hf1k0 : hf0k0, g, 0,0,0);
          g = __builtin_amdgcn_mfma_f32_16x16x32_bf16(a1, mh ? hf1k1 : hf0k1, g, 0,0,0);
          int m = mh*16 + lr;
          unsigned int p0 = pkbf(g[0], g[1]);
          unsigned int p1 = pkbf(g[2], g[3]);
          int byt = ((((m*4 + q8)*32 + ol) << 4) + jj*2) ^ ((m & 7) << 4);
          uint2 pv; pv.x = p0; pv.y = p1;
          *(uint2*)((char*)Gl + byt) = pv;
        }
      }
      // t A-fragments for this k-quarter (latency spans the barrier)
      short8v th0, th1, th2, th3, tw0, tw1, tw2, tw3;
      {
        size_t kqo = (size_t)kq*32 + quad*8;
        int e0 = eidl[j0+0][lr], e1 = eidl[j0+1][lr];
        int e2 = eidl[j0+2][lr], e3 = eidl[j0+3][lr];
        th0 = *(const short8v*)(thi + (size_t)e0*EH + kqo);
        tw0 = *(const short8v*)(tlo + (size_t)e0*EH + kqo);
        th1 = *(const short8v*)(thi + (size_t)e1*EH + kqo);
        tw1 = *(const short8v*)(tlo + (size_t)e1*EH + kqo);
        th2 = *(const short8v*)(thi + (size_t)e2*EH + kqo);
        tw2 = *(const short8v*)(tlo + (size_t)e2*EH + kqo);
        th3 = *(const short8v*)(thi + (size_t)e3*EH + kqo);
        tw3 = *(const short8v*)(tlo + (size_t)e3*EH + kqo);
      }
      __syncthreads();                   // Gl ready
      // GEMM2: per src, per o-tile: acc += T @ Gl
      #pragma unroll
      for (int j = 0; j < 4; ++j){
        int m = j0 + j;
        int swz = (m & 7) << 4;
        short8v thj = (j==0)?th0:(j==1)?th1:(j==2)?th2:th3;
        short8v twj = (j==0)?tw0:(j==1)?tw1:(j==2)?tw2:tw3;
        #pragma unroll
        for (int ot = 0; ot < 2; ++ot){
          int byt = (((m*4 + quad)*32 + ot*16 + lr) << 4) ^ swz;
          short8v gf = *(const short8v*)((const char*)Gl + byt);
          acc[j][ot] = __builtin_amdgcn_mfma_f32_16x16x32_bf16(thj, gf, acc[j][ot], 0,0,0);
          acc[j][ot] = __builtin_amdgcn_mfma_f32_16x16x32_bf16(twj, gf, acc[j][ot], 0,0,0);
        }
      }
    }
    // flush: rows = e_slot = quad*4+reg, cols o = oh*32 + ot*16 + lr
    #pragma unroll
    for (int j = 0; j < 4; ++j){
      int m = j0 + j;
      #pragma unroll
      for (int ot = 0; ot < 2; ++ot){
        int o = oh*32 + ot*16 + lr;
        float bb = bhl[m*66 + o];
        #pragma unroll
        for (int reg = 0; reg < 4; ++reg){
          int sl = quad*4 + reg;
          int eid = eidl[m][sl];
          if (eid < NE) msg[(size_t)posl[m][sl]*DD + o] = acc[j][ot][reg] + bb;
        }
      }
    }
  }
}

// ---------- per step, COOPERATIVE: k_red + grid.sync + gru_one in ONE dispatch.
// 235 blocks x 512 thr, 1 block/CU (155 KB LDS) -> all co-resident.
// Phase 1: dst-major mean-reduce (contiguous msg stream) + BN partials
//          (ls/ls2 aliased into the phase-2 gate buffer).
// grid.sync(): device-scope visibility of rst/part across XCDs.
// Phase 2: BN fold (4-way parallel) + gru_pre + gru_gemm + gru_fin in-block.
__global__ __launch_bounds__(512) void k_tail(
    const float* __restrict__ msg, const int* __restrict__ rowp_d,
    const float* __restrict__ invd, const float* __restrict__ cbias,
    float* __restrict__ rst, float* __restrict__ part,
    const float* __restrict__ gamma, const float* __restrict__ beta,
    ushort_t* __restrict__ ab, const ushort_t* __restrict__ wg,
    const float* __restrict__ bih, const float* __restrict__ bhh,
    float* __restrict__ hid, float* __restrict__ out, int write_out){
  __shared__ __align__(16) ushort_t As[64][136];   // 17.4 KB
  __shared__ __align__(16) ushort_t Bs[256][136];  // 69.6 KB
  __shared__ float gl[64*257];                     // 65.8 KB gates (pad 257)
  __shared__ float scl[64], sft[64];
  __shared__ float shp[4][128];                    // 2 KB fold partials
  int t = threadIdx.x;
  int blk = blockIdx.x;
  int r0 = blk * 64;

  // ---- phase 1: mean-reduce + BN partials (ls/ls2 alias gl)
  {
    float* ls  = gl;          // [512]
    float* ls2 = gl + 512;    // [512]
    int o = t & 63, gg = t >> 6;
    float cb = cbias[o];
    float s = 0.f, s2 = 0.f;
    int nbase = blk*64 + gg*8;
    int rp[9];
    #pragma unroll
    for (int k = 0; k < 9; ++k){
      int idx = nbase + k; if (idx > NN) idx = NN;
      rp[k] = rowp_d[idx];
    }
    #pragma unroll 1
    for (int j = 0; j < 8; ++j){
      int n = nbase + j;
      if (n >= NN) break;
      int b = rp[j], e = rp[j+1];
      float a0 = 0.f, a1 = 0.f, a2 = 0.f, a3 = 0.f;
      int i = b;
      for (; i + 3 < e; i += 4){
        a0 += msg[(size_t)i*DD + o];
        a1 += msg[(size_t)(i+1)*DD + o];
        a2 += msg[(size_t)(i+2)*DD + o];
        a3 += msg[(size_t)(i+3)*DD + o];
      }
      for (; i < e; ++i) a0 += msg[(size_t)i*DD + o];
      float x = ((a0 + a1) + (a2 + a3)) * invd[n] + cb;
      rst[(size_t)n*DD + o] = x;
      s += x; s2 += x*x;
    }
    ls[t] = s; ls2[t] = s2;
    __syncthreads();
    if (t < 64){
      float a = 0.f;
      #pragma unroll
      for (int g = 0; g < 8; ++g) a += ls[g*64 + t];
      part[blk*128 + t] = a;
    } else if (t < 128){
      int o2 = t - 64;
      float a = 0.f;
      #pragma unroll
      for (int g = 0; g < 8; ++g) a += ls2[g*64 + o2];
      part[blk*128 + 64 + o2] = a;
    }
  }

  cg::this_grid().sync();   // rst/part globally visible (device-scope)

  // ---- phase 2: BN fold (4-way parallel) -> scale/shift
  {
    int tg = t >> 7, tc = t & 127;
    float s0 = 0.f, s1 = 0.f;
    int b = tg;
    for (; b + 4 < NRB; b += 8){ s0 += part[b*128 + tc]; s1 += part[(b+4)*128 + tc]; }
    for (; b < NRB; b += 4) s0 += part[b*128 + tc];
    shp[tg][tc] = s0 + s1;
  }
  __syncthreads();
  if (t < 64){
    float su = shp[0][t] + shp[1][t] + shp[2][t] + shp[3][t];
    float sq = shp[0][64+t] + shp[1][64+t] + shp[2][64+t] + shp[3][64+t];
    float mu = su / (float)NN;
    float var = sq / (float)NN - mu*mu;
    if (var < 0.f) var = 0.f;
    float rsq = rsqrtf(var + 1e-5f);
    float sc = rsq * gamma[t];
    scl[t] = sc;
    sft[t] = beta[t] - mu*sc;
  }
  int wv = t >> 6, lane = t & 63;
  int lr = lane & 15, quad = lane >> 4;
  int n0 = wv * 32;                      // this wave's 32 output cols
  float4v acc[4][2];
  #pragma unroll
  for (int mt = 0; mt < 4; ++mt)
    #pragma unroll
    for (int nt = 0; nt < 2; ++nt) acc[mt][nt] = (float4v){0.f,0.f,0.f,0.f};
  for (int kt = 0; kt < 3; ++kt){
    __syncthreads();
    #pragma unroll
    for (int it = 0; it < 2; ++it){      // As: 64 rows x 16 chunks of 8
      int cid = t + it*512;
      int r = cid >> 4, ko = (cid & 15) * 8;
      int gm = r0 + r; if (gm >= NN) gm = NN-1;
      if (ko < 64){
        // m-part: compute from rst (kt 0,2: m_hi; kt 1: m_lo)
        float4 x0 = *(const float4*)(rst + (size_t)gm*DD + ko);
        float4 x1 = *(const float4*)(rst + (size_t)gm*DD + ko + 4);
        float xv[8] = {x0.x,x0.y,x0.z,x0.w,x1.x,x1.y,x1.z,x1.w};
        ushort_t u[8];
        #pragma unroll
        for (int jj = 0; jj < 8; ++jj){
          float m = fmaxf(xv[jj]*scl[ko+jj] + sft[ko+jj], 0.f);
          ushort_t mh = fsb(m);
          u[jj] = (kt == 1) ? fsb(m - bsf(mh)) : mh;
        }
        *(uint4*)&As[r][ko] = *(const uint4*)u;
      } else {
        // h-part from ab (kt0: h_hi@64, kt1: h_lo@192, kt2: h_hi@320)
        *(uint4*)&As[r][ko] = *(const uint4*)(ab + (size_t)gm*KAB + kt*128 + ko);
      }
    }
    #pragma unroll
    for (int it = 0; it < 8; ++it){      // Bs: 256 rows x 16 chunks of 8
      int cid = t + it*512;
      int rB = cid >> 4, ko = (cid & 15) * 8;
      *(uint4*)&Bs[rB][ko] = *(const uint4*)(wg + (size_t)rB*KAB + kt*128 + ko);
    }
    __syncthreads();
    #pragma unroll
    for (int ks = 0; ks < 4; ++ks){
      short8v a[4];
      #pragma unroll
      for (int mt = 0; mt < 4; ++mt)
        a[mt] = *(const short8v*)&As[mt*16 + lr][ks*32 + quad*8];
      #pragma unroll
      for (int nt = 0; nt < 2; ++nt){
        short8v b = *(const short8v*)&Bs[n0 + nt*16 + lr][ks*32 + quad*8];
        #pragma unroll
        for (int mt = 0; mt < 4; ++mt)
          acc[mt][nt] = __builtin_amdgcn_mfma_f32_16x16x32_bf16(a[mt], b, acc[mt][nt], 0,0,0);
      }
    }
  }
  // D -> gate LDS: row = mt*16 + quad*4 + reg, col = n0 + nt*16 + lr
  #pragma unroll
  for (int mt = 0; mt < 4; ++mt)
    #pragma unroll
    for (int nt = 0; nt < 2; ++nt){
      int col = n0 + nt*16 + lr;
      #pragma unroll
      for (int reg = 0; reg < 4; ++reg)
        gl[(mt*16 + quad*4 + reg)*257 + col] = acc[mt][nt][reg];
    }
  __syncthreads();
  // GRU nonlinearity + h update, 64 rows x 64 o
  for (int idx = t; idx < 64*64; idx += 512){
    int row = idx >> 6, o = idx & 63;
    int v = r0 + row;
    if (v >= NN) break;
    const float* g = &gl[row*257];
    float aR  = g[o]       + bih[o]      + bhh[o];
    float aZ  = g[64 + o]  + bih[64+o]   + bhh[64+o];
    float aNi = g[128 + o] + bih[128+o];
    float aNh = g[192 + o] + bhh[128+o];
    float hprev = hid[(size_t)v*DD + o];
    float r = 1.f/(1.f+__expf(-aR));
    float z = 1.f/(1.f+__expf(-aZ));
    float n = tanhf(aNi + r*aNh);
    float hnew = (1.f - z)*n + z*hprev;
    hid[(size_t)v*DD + o] = hnew;
    ushort_t hh = fsb(hnew);
    float hl = hnew - bsf(hh);
    ab[(size_t)v*KAB + 64 + o]  = hh;
    ab[(size_t)v*KAB + 192 + o] = fsb(hl);
    ab[(size_t)v*KAB + 320 + o] = hh;
    if (write_out) out[(size_t)v*DD + o] = hnew;
  }
}

extern "C" void kernel_launch(void* const* d_in, const int* in_sizes, int n_in,
                              void* d_out, int out_size, void* d_ws, size_t ws_size,
                              hipStream_t stream){
  (void)out_size; (void)ws_size;
  float* out = (float*)d_out;

  // resolve input positions by size (== dict order on this instance)
  int p_nf=-1,p_ef=-1,p_src=-1,p_dst=-1,p_Wp=-1,p_bp=-1,p_W1=-1,p_b1=-1,
      p_W2=-1,p_b2=-1,p_cb=-1,p_gam=-1,p_bet=-1,p_Wih=-1,p_Whh=-1,p_bih=-1,p_bhh=-1;
  int c60000=0,c64=0,c12288=0,c192=0;
  for (int i = 0; i < n_in; ++i){
    switch (in_sizes[i]){
      case 1110000: p_nf = i; break;
      case 720000:  p_ef = i; break;
      case 60000:   if (c60000++ == 0) p_src = i; else p_dst = i; break;
      case 4736:    p_Wp = i; break;
      case 64:      { if (c64==0) p_bp=i; else if (c64==1) p_cb=i;
                      else if (c64==2) p_gam=i; else p_bet=i; c64++; } break;
      case 1536:    p_W1 = i; break;
      case 128:     p_b1 = i; break;
      case 524288:  p_W2 = i; break;
      case 4096:    p_b2 = i; break;
      case 12288:   if (c12288++ == 0) p_Wih = i; else p_Whh = i; break;
      case 192:    if (c192++ == 0) p_bih = i; else p_bhh = i; break;
      default: break;
    }
  }

  char* p = (char*)d_ws;
  auto alloc = [&](size_t bytes)->char*{
    char* r = p; p += (bytes + 255) & ~(size_t)255; return r;
  };
  int* flags = (int*)alloc(256);
  const int FPOS[15] = {p_nf,p_ef,p_Wp,p_bp,p_W1,p_b1,p_W2,p_b2,p_cb,p_gam,p_bet,
                        p_Wih,p_Whh,p_bih,p_bhh};
  CanonArgs ca;
  int maxn = 0;
  for (int j = 0; j < 15; ++j){
    int n = in_sizes[FPOS[j]];
    ca.in[j]  = d_in[FPOS[j]];
    ca.out[j] = (float*)alloc((size_t)n * 4);
    ca.n[j]   = n;
    if (n > maxn) maxn = n;
  }
  const float* nf  = ca.out[0];  const float* ef  = ca.out[1];
  const float* Wp  = ca.out[2];  const float* bp  = ca.out[3];
  const float* W1  = ca.out[4];  const float* b1  = ca.out[5];
  const float* W2  = ca.out[6];  const float* b2  = ca.out[7];
  const float* cb  = ca.out[8];  const float* gam = ca.out[9];
  const float* bet = ca.out[10]; const float* Wih = ca.out[11];
  const float* Whh = ca.out[12]; const float* bih = ca.out[13];
  const float* bhh = ca.out[14];
  int* srcc = (int*)alloc((size_t)NE*4);
  int* dstc = (int*)alloc((size_t)NE*4);

  ushort_t* thi   = (ushort_t*)alloc((size_t)(NE+1)*EH*2); // 15.4 MB
  ushort_t* tlo   = (ushort_t*)alloc((size_t)(NE+1)*EH*2); // 15.4 MB
  ushort_t* w2q   = (ushort_t*)alloc((size_t)NG*DD*2);     // 1.05 MB
  ushort_t* w2b   = (ushort_t*)alloc((size_t)DD*DD*2);     // 8 KB
  float* hid      = (float*)alloc((size_t)NN*DD*4);
  ushort_t* ab    = (ushort_t*)alloc((size_t)NN*KAB*2);    // 11.5 MB split activations
  ushort_t* wg    = (ushort_t*)alloc((size_t)256*KAB*2);   // 0.2 MB split GRU weights
  float* rst      = (float*)alloc((size_t)NN*DD*4);
  float* msg      = (float*)alloc((size_t)NE*DD*4);        // 15.4 MB per-edge messages
  float* part     = (float*)alloc((size_t)NRB*128*4);
  int* degall     = (int*)alloc((size_t)4*NN*4);
  int* deg  = degall;           // dst degrees
  int* curd = degall + NN;      // dst scatter cursor
  int* deg2 = degall + 2*NN; int* cursor2 = degall + 3*NN;
  float* invd = (float*)alloc((size_t)NN*4);
  int* rowp_d = (int*)alloc((size_t)(NN+1)*4);
  int* eidx_d = (int*)alloc((size_t)NE*4);
  int* epos   = (int*)alloc((size_t)NE*4);
  int* rowp2  = (int*)alloc((size_t)(NN+1)*4);
  float* invd2= (float*)alloc((size_t)NN*4);
  int* eidx2  = (int*)alloc((size_t)NE*4);
  int* tnode  = (int*)alloc((size_t)NTMAX*4);
  int* tbase  = (int*)alloc((size_t)NTMAX*4);
  int* tcnt   = (int*)alloc((size_t)NTMAX*4);
  int* ntb    = (int*)alloc(256);

  k_sniff<<<1, 256, 0, stream>>>((const ushort_t*)d_in[p_nf], (const int*)d_in[p_dst], flags);
  k_canon_all<<<dim3((maxn+255)/256, 15), 256, 0, stream>>>(ca, flags);
  k_canoni2<<<dim3((NE+255)/256, 2), 256, 0, stream>>>(d_in[p_src], d_in[p_dst],
                                                       srcc, dstc, flags);

  k_proj <<<NN/4,  256, 0, stream>>>(nf, Wp, bp, hid, ab);
  k_emlp <<<NE/2,  256, 0, stream>>>(ef, W1, b1, thi, tlo);
  k_zpad <<<1, 128, 0, stream>>>(thi, tlo);
  k_w2q  <<<(NG*DD + DD*DD + 255)/256, 256, 0, stream>>>(W2, b2, w2q, w2b);
  k_wgru <<<(256*KAB+255)/256, 256, 0, stream>>>(Wih, Whh, wg);
  k_zero <<<(4*NN+255)/256, 256, 0, stream>>>(degall, 4*NN);
  k_deg2 <<<dim3((NE+255)/256, 2), 256, 0, stream>>>(dstc, srcc, deg, deg2);
  k_scan2<<<2, 256, 0, stream>>>(deg, rowp_d, invd, deg2, rowp2, invd2);
  k_scatter2<<<dim3((NE+255)/256, 2), 256, 0, stream>>>(dstc, rowp_d, curd, eidx_d,
                                                        epos, srcc, rowp2, cursor2, eidx2);
  k_tiles<<<1, 256, 0, stream>>>(rowp2, tnode, tbase, tcnt, ntb);

  for (int s = 0; s < NSTEPS; ++s){
    k_fused7<<<NFB, 512, 0, stream>>>(ab, w2q, w2b, thi, tlo,
                                      tnode, tbase, tcnt, ntb, eidx2, epos, msg);
    int wout = (s == NSTEPS-1) ? 1 : 0;
    void* targs[] = {(void*)&msg, (void*)&rowp_d, (void*)&invd, (void*)&cb,
                     (void*)&rst, (void*)&part, (void*)&gam, (void*)&bet,
                     (void*)&ab, (void*)&wg, (void*)&bih, (void*)&bhh,
                     (void*)&hid, (void*)&out, (void*)&wout};
    hipLaunchCooperativeKernel((const void*)k_tail, dim3(NRB), dim3(512),
                               targs, 0, stream);
  }
}

// Round 16
// 940.717 us; speedup vs baseline: 1.2829x; 1.2829x over previous
//
#include <hip/hip_runtime.h>
#include <hip/hip_bf16.h>
#include <math.h>

#define NN 15000      // nodes
#define NE 60000      // edges
#define DIN 74
#define DEIN 12
#define DD 64         // node feat dim
#define EH 128        // edge hidden
#define NG 8192       // EH*DD
#define NSTEPS 6
#define NRB 235       // ceil(NN/64)  (k_red blocks / BN partials)
#define NGB 235       // ceil(NN/64)  (k_gru_one blocks)
#define KAB 384       // GRU split-A width: [m_hi,h_hi,m_lo,h_lo,m_hi,h_hi]
#define NTMAX 18752   // >= NN + NE/16 tiles (deg split into <=16-edge tiles)
#define NFB 586       // ceil(18750/32) fused blocks

typedef unsigned short ushort_t;
typedef __attribute__((ext_vector_type(8))) short short8v;
typedef __attribute__((ext_vector_type(4))) float float4v;

__device__ __forceinline__ float bsf(unsigned short u){
  union { unsigned int i; float f; } v; v.i = ((unsigned int)u) << 16; return v.f;
}
__device__ __forceinline__ unsigned short fsb(float f){
  union { float f; unsigned int i; } v; v.f = f;
  unsigned int x = v.i;
  return (unsigned short)((x + 0x7FFFu + ((x >> 16) & 1u)) >> 16);
}
// packed RNE f32x2 -> bf16x2 (same rounding as fsb, HW v_cvt_pk_bf16_f32)
__device__ __forceinline__ unsigned int pkbf(float a, float b){
  __hip_bfloat162 r = __float22bfloat162_rn(make_float2(a, b));
  union { __hip_bfloat162 h; unsigned int u; } v; v.h = r; return v.u;
}

// ---------- dtype sniff
__global__ void k_sniff(const ushort_t* __restrict__ nf16,
                        const int* __restrict__ dsti, int* __restrict__ flags){
  __shared__ int cnt[2];
  int t = threadIdx.x;
  if (t < 2) cnt[t] = 0;
  __syncthreads();
  int bad = 0;
  for (int i = t; i < 1024; i += 256){
    unsigned short u = nf16[2*i];
    int e = (u >> 7) & 0xFF;
    if (e < 96 || e > 159) bad++;
  }
  if (bad) atomicAdd(&cnt[0], bad);
  if (t < 256 && dsti[2*t+1] == 0) atomicAdd(&cnt[1], 1);
  __syncthreads();
  if (t == 0){
    flags[0] = (cnt[0] > 300) ? 1 : 0;
    flags[1] = (cnt[1] > 250) ? 1 : 0;
  }
}

// ---------- batched canonicalization: 15 tensors in one dispatch
struct CanonArgs {
  const void* in[15];
  float* out[15];
  int n[15];
};
__global__ void k_canon_all(CanonArgs a, const int* __restrict__ flags){
  int j = blockIdx.y;
  int n = a.n[j];
  int fp32 = flags[0];
  const void* in = a.in[j];
  float* out = a.out[j];
  for (int i = blockIdx.x*256 + threadIdx.x; i < n; i += gridDim.x*256){
    if (fp32) out[i] = ((const float*)in)[i];
    else      out[i] = bsf(((const ushort_t*)in)[i]);
  }
}
// both index arrays in one dispatch (blockIdx.y = which)
__global__ void k_canoni2(const void* __restrict__ in0, const void* __restrict__ in1,
                          int* __restrict__ out0, int* __restrict__ out1,
                          const int* __restrict__ flags){
  int i = blockIdx.x*256 + threadIdx.x;
  if (i >= NE) return;
  const void* in = blockIdx.y ? in1 : in0;
  int* out = blockIdx.y ? out1 : out0;
  long long v = flags[1] ? ((const long long*)in)[i]
                         : (long long)((const int*)in)[i];
  int vi = (int)v;
  if (vi < 0) vi = 0;
  if (vi >= NN) vi = NN-1;
  out[i] = vi;
}

// ---------- one-time: h0 = relu(nf @ W_proj + b_proj) -> fp32 hid + ab h-parts
__global__ void k_proj(const float* __restrict__ nf, const float* __restrict__ Wp,
                       const float* __restrict__ bp, float* __restrict__ hid,
                       ushort_t* __restrict__ ab){
  __shared__ float nfl[4][DIN];
  int t = threadIdx.x, blk = blockIdx.x;
  for (int idx = t; idx < 4*DIN; idx += 256){
    int vl = idx / DIN, i = idx - vl*DIN;
    nfl[vl][i] = nf[(size_t)(blk*4+vl)*DIN + i];
  }
  __syncthreads();
  int vl = t >> 6, o = t & 63;
  int v = blk*4 + vl;
  float acc = bp[o];
  for (int i = 0; i < DIN; ++i) acc += nfl[vl][i] * Wp[i*DD + o];
  float r = fmaxf(acc, 0.f);
  hid[(size_t)v*DD + o] = r;
  ushort_t hh = fsb(r);
  float hl = r - bsf(hh);
  ab[(size_t)v*KAB + 64 + o]  = hh;        // h_hi
  ab[(size_t)v*KAB + 192 + o] = fsb(hl);   // h_lo
  ab[(size_t)v*KAB + 320 + o] = hh;        // h_hi copy (pairs W_lo)
}

// ---------- one-time: t = relu(ef @ W_e1 + b_e1), split bf16 hi/lo
__global__ void k_emlp(const float* __restrict__ ef, const float* __restrict__ W1,
                       const float* __restrict__ b1, ushort_t* __restrict__ thi,
                       ushort_t* __restrict__ tlo){
  __shared__ float efl[2][DEIN];
  int t = threadIdx.x, blk = blockIdx.x;
  if (t < 2*DEIN){
    int el = t / DEIN, i = t - el*DEIN;
    efl[el][i] = ef[(size_t)(blk*2+el)*DEIN + i];
  }
  __syncthreads();
  int el = t >> 7, c = t & 127;
  float acc = b1[c];
  for (int i = 0; i < DEIN; ++i) acc += efl[el][i] * W1[i*EH + c];
  float tv = fmaxf(acc, 0.f);
  ushort_t hiv = fsb(tv);
  size_t off = (size_t)(blk*2+el)*EH + c;
  thi[off] = hiv;
  tlo[off] = fsb(tv - bsf(hiv));
}
__global__ void k_zpad(ushort_t* __restrict__ thi, ushort_t* __restrict__ tlo){
  int t = threadIdx.x;   // 128
  thi[(size_t)NE*EH + t] = 0;
  tlo[(size_t)NE*EH + t] = 0;
}

// ---------- one-time: w2q rows ordered [kq(4)][o(64)][k_local(32)] x i(64)
// plus w2b[o][i] bias fold rows
__global__ void k_w2q(const float* __restrict__ W2, const float* __restrict__ b2,
                      ushort_t* __restrict__ w2q, ushort_t* __restrict__ w2b){
  int idx = blockIdx.x*256 + threadIdx.x;
  if (idx < NG*DD){
    int n = idx >> 6, i = idx & 63;
    int kq = n >> 11, rem = n & 2047;
    int o = rem >> 5, kl = rem & 31;
    int kg = kq*32 + kl;
    w2q[idx] = fsb(W2[(size_t)kg*4096 + i*64 + o]);
  } else if (idx < NG*DD + DD*DD){
    int r = idx - NG*DD;
    int o = r >> 6, i = r & 63;
    w2b[r] = fsb(b2[i*64 + o]);
  }
}

// ---------- one-time: GRU split weight matrix wg[c][k], c in [0,256), k in [0,384)
__global__ void k_wgru(const float* __restrict__ Wih, const float* __restrict__ Whh,
                       ushort_t* __restrict__ wg){
  int pos = blockIdx.x*256 + threadIdx.x;
  if (pos >= 256*KAB) return;
  int c = pos / KAB, k = pos - c*KAB;
  int kb = k >> 6, i = k & 63;
  int g = c >> 6, o = c & 63;
  float w = 0.f;
  if ((kb & 1) == 0){          // m-side: Wih
    if (g == 0)      w = Wih[(size_t)(o)*64 + i];
    else if (g == 1) w = Wih[(size_t)(64+o)*64 + i];
    else if (g == 2) w = Wih[(size_t)(128+o)*64 + i];
  } else {                     // h-side: Whh
    if (g == 0)      w = Whh[(size_t)(o)*64 + i];
    else if (g == 1) w = Whh[(size_t)(64+o)*64 + i];
    else if (g == 3) w = Whh[(size_t)(128+o)*64 + i];
  }
  ushort_t hi = fsb(w);
  wg[pos] = (kb >= 4) ? fsb(w - bsf(hi)) : hi;
}

// ---------- CSR build (both directions, merged dispatches)
__global__ void k_zero(int* __restrict__ p, int n){
  int i = blockIdx.x*256 + threadIdx.x;
  if (i < n) p[i] = 0;
}
__global__ void k_deg2(const int* __restrict__ a0, const int* __restrict__ a1,
                       int* __restrict__ d0, int* __restrict__ d1){
  int e = blockIdx.x*256 + threadIdx.x;
  if (e < NE){
    if (blockIdx.y == 0) atomicAdd(&d0[a0[e]], 1);
    else                 atomicAdd(&d1[a1[e]], 1);
  }
}
__global__ void k_scan2(const int* __restrict__ degA, int* __restrict__ rowpA,
                        float* __restrict__ invdA,
                        const int* __restrict__ degB, int* __restrict__ rowpB,
                        float* __restrict__ invdB){
  const int* deg = blockIdx.x ? degB : degA;
  int* rowp      = blockIdx.x ? rowpB : rowpA;
  float* invd    = blockIdx.x ? invdB : invdA;
  __shared__ int ssum[256];
  int t = threadIdx.x;
  const int STRIP = (NN + 255) / 256;
  int lo = t*STRIP, hi = (lo + STRIP < NN) ? lo + STRIP : NN;
  int s = 0;
  for (int i = lo; i < hi; ++i) s += deg[i];
  ssum[t] = s;
  __syncthreads();
  if (t == 0){
    int acc = 0;
    for (int i = 0; i < 256; ++i){ int v = ssum[i]; ssum[i] = acc; acc += v; }
  }
  __syncthreads();
  int acc = ssum[t];
  for (int i = lo; i < hi; ++i){
    rowp[i] = acc;
    int d = deg[i];
    invd[i] = (d > 0) ? 1.0f/(float)d : 0.0f;
    acc += d;
  }
  if (t == 255) rowp[NN] = acc;
}
__global__ void k_scatter2(const int* __restrict__ dstc, const int* __restrict__ rowpD,
                           int* __restrict__ curD, int* __restrict__ eidxD,
                           int* __restrict__ epos,
                           const int* __restrict__ srcc, const int* __restrict__ rowpS,
                           int* __restrict__ curS, int* __restrict__ eidxS){
  int e = blockIdx.x*256 + threadIdx.x;
  if (e >= NE) return;
  if (blockIdx.y == 0){
    int d = dstc[e];
    int pos = atomicAdd(&curD[d], 1);
    int slot = rowpD[d] + pos;
    eidxD[slot] = e;
    epos[e] = slot;
  } else {
    int d = srcc[e];
    int pos = atomicAdd(&curS[d], 1);
    eidxS[rowpS[d] + pos] = e;
  }
}

// ---------- one-time: split src CSR into tiles of <=16 edges
__global__ void k_tiles(const int* __restrict__ rowp, int* __restrict__ tnode,
                        int* __restrict__ tbase, int* __restrict__ tcnt,
                        int* __restrict__ ntb){
  __shared__ int ss[256];
  int t = threadIdx.x;
  const int STRIP = (NN + 255) / 256;
  int lo = t*STRIP, hi = lo + STRIP; if (hi > NN) hi = NN;
  int c = 0;
  for (int i = lo; i < hi; ++i){
    int deg = rowp[i+1] - rowp[i];
    c += (deg + 15) >> 4;
  }
  ss[t] = c;
  __syncthreads();
  if (t == 0){
    int a = 0;
    for (int i = 0; i < 256; ++i){ int v = ss[i]; ss[i] = a; a += v; }
    ntb[0] = a;
  }
  __syncthreads();
  int pos = ss[t];
  for (int i = lo; i < hi; ++i){
    int b = rowp[i], deg = rowp[i+1] - b;
    for (int r = 0; r < deg; r += 16){
      tnode[pos] = i; tbase[pos] = b + r;
      int c2 = deg - r; tcnt[pos] = (c2 > 16) ? 16 : c2;
      ++pos;
    }
  }
}

// ---------- FUSED per step, all-MFMA, ATOMIC-FREE (proven form):
// block = 32 src tiles. Per (oh, kq) chunk:
//   GEMM1: Gl[m][k32][o32] = w2q-chunk @ h (v_cvt_pk pack, XOR-swizzled 8B wr)
//   GEMM2: acc[j][ot] += T @ Gl (B-frags)
// flush per o-half: coalesced stores of msg at DST-CSR slot epos[e].
__global__ __launch_bounds__(512,4) void k_fused7(
    const ushort_t* __restrict__ ab, const ushort_t* __restrict__ w2q,
    const ushort_t* __restrict__ w2b, const ushort_t* __restrict__ thi,
    const ushort_t* __restrict__ tlo,
    const int* __restrict__ tnode, const int* __restrict__ tbase,
    const int* __restrict__ tcnt, const int* __restrict__ ntb,
    const int* __restrict__ eidx, const int* __restrict__ epos,
    float* __restrict__ msg){
  __shared__ __align__(16) ushort_t Gl[32768];   // [m32][q8:4][o32][8] = 64 KB
  __shared__ float bhl[32*66];                   // 8.25 KB bias tile (pad 66)
  __shared__ int nodl[32], cntl[32], basel[32];
  __shared__ int eidl[32][16];
  __shared__ int posl[32][16];

  int tid = threadIdx.x;
  int nt = ntb[0];
  int T0 = blockIdx.x * 32;
  if (T0 >= nt) return;
  int wv = tid >> 6, lane = tid & 63;
  int lr = lane & 15, quad = lane >> 4;

  if (tid < 32){
    int gt = T0 + tid;
    int node = 0, base = 0, cnt = 0;
    if (gt < nt){ node = tnode[gt]; base = tbase[gt]; cnt = tcnt[gt]; }
    nodl[tid] = node; basel[tid] = base; cntl[tid] = cnt;
  }
  __syncthreads();
  {
    int j = tid >> 4, sl = tid & 15;
    int eid = NE, ps = 0;
    if (sl < cntl[j]){
      eid = eidx[basel[j] + sl];
      ps = epos[eid];
    }
    eidl[j][sl] = eid;
    posl[j][sl] = ps;
  }
  // h_hi B-fragments for both m-halves (col = lane&15 = m, k=i at quad*8)
  short8v hf0k0, hf0k1, hf1k0, hf1k1;
  {
    int n0 = nodl[lr], n1 = nodl[16 + lr];
    hf0k0 = *(const short8v*)(ab + (size_t)n0*KAB + 64 + quad*8);
    hf0k1 = *(const short8v*)(ab + (size_t)n0*KAB + 96 + quad*8);
    hf1k0 = *(const short8v*)(ab + (size_t)n1*KAB + 64 + quad*8);
    hf1k1 = *(const short8v*)(ab + (size_t)n1*KAB + 96 + quad*8);
  }
  // bias tile bh[m][o] = h @ b2 via MFMA (A = w2b rows o, B = h)
  {
    int ot = wv & 3, mh = wv >> 2;
    float4v ba = (float4v){0.f,0.f,0.f,0.f};
    short8v a0 = *(const short8v*)(w2b + (size_t)(ot*16 + lr)*DD + quad*8);
    short8v a1 = *(const short8v*)(w2b + (size_t)(ot*16 + lr)*DD + 32 + quad*8);
    ba = __builtin_amdgcn_mfma_f32_16x16x32_bf16(a0, mh ? hf1k0 : hf0k0, ba, 0,0,0);
    ba = __builtin_amdgcn_mfma_f32_16x16x32_bf16(a1, mh ? hf1k1 : hf0k1, ba, 0,0,0);
    #pragma unroll
    for (int reg = 0; reg < 4; ++reg)
      bhl[(mh*16 + lr)*66 + ot*16 + quad*4 + reg] = ba[reg];
  }

  int j0 = wv*4;                         // this wave's 4 src tiles
  for (int oh = 0; oh < 2; ++oh){
    float4v acc[4][2];
    #pragma unroll
    for (int j = 0; j < 4; ++j)
      #pragma unroll
      for (int ot = 0; ot < 2; ++ot)
        acc[j][ot] = (float4v){0.f,0.f,0.f,0.f};
    for (int kq = 0; kq < 4; ++kq){
      __syncthreads();                   // Gl consumable -> writable
      // GEMM1: this wave's 8 n-tiles (128 consecutive w2q rows)
      #pragma unroll 4
      for (int it = 0; it < 8; ++it){
        int tile = wv*8 + it;
        int nrow = kq*2048 + oh*1024 + tile*16 + lr;
        const ushort_t* arow = w2q + (size_t)nrow*DD;
        short8v a0 = *(const short8v*)(arow + quad*8);
        short8v a1 = *(const short8v*)(arow + 32 + quad*8);
        int ol = tile >> 1;
        int klb = ((tile & 1) << 4) + quad*4;
        int q8 = klb >> 3, jj = klb & 7;
        #pragma unroll
        for (int mh = 0; mh < 2; ++mh){
          float4v g = (float4v){0.f,0.f,0.f,0.f};
          g = __builtin_amdgcn_mfma_f32_16x16x32_bf16(a0, mh ? hf1k0 : hf0k0, g, 0,0,0);
          g = __builtin_amdgcn_mfma_f32_16x16x32_bf16(a1, mh ? hf1k1 : hf0k1, g, 0,0,0);
          int m = mh*16 + lr;
          unsigned int p0 = pkbf(g[0], g[1]);
          unsigned int p1 = pkbf(g[2], g[3]);
          int byt = ((((m*4 + q8)*32 + ol) << 4) + jj*2) ^ ((m & 7) << 4);
          uint2 pv; pv.x = p0; pv.y = p1;
          *(uint2*)((char*)Gl + byt) = pv;
        }
      }
      // t A-fragments for this k-quarter (latency spans the barrier)
      short8v th0, th1, th2, th3, tw0, tw1, tw2, tw3;
      {
        size_t kqo = (size_t)kq*32 + quad*8;
        int e0 = eidl[j0+0][lr], e1 = eidl[j0+1][lr];
        int e2 = eidl[j0+2][lr], e3 = eidl[j0+3][lr];
        th0 = *(const short8v*)(thi + (size_t)e0*EH + kqo);
        tw0 = *(const short8v*)(tlo + (size_t)e0*EH + kqo);
        th1 = *(const short8v*)(thi + (size_t)e1*EH + kqo);
        tw1 = *(const short8v*)(tlo + (size_t)e1*EH + kqo);
        th2 = *(const short8v*)(thi + (size_t)e2*EH + kqo);
        tw2 = *(const short8v*)(tlo + (size_t)e2*EH + kqo);
        th3 = *(const short8v*)(thi + (size_t)e3*EH + kqo);
        tw3 = *(const short8v*)(tlo + (size_t)e3*EH + kqo);
      }
      __syncthreads();                   // Gl ready
      // GEMM2: per src, per o-tile: acc += T @ Gl
      #pragma unroll
      for (int j = 0; j < 4; ++j){
        int m = j0 + j;
        int swz = (m & 7) << 4;
        short8v thj = (j==0)?th0:(j==1)?th1:(j==2)?th2:th3;
        short8v twj = (j==0)?tw0:(j==1)?tw1:(j==2)?tw2:tw3;
        #pragma unroll
        for (int ot = 0; ot < 2; ++ot){
          int byt = (((m*4 + quad)*32 + ot*16 + lr) << 4) ^ swz;
          short8v gf = *(const short8v*)((const char*)Gl + byt);
          acc[j][ot] = __builtin_amdgcn_mfma_f32_16x16x32_bf16(thj, gf, acc[j][ot], 0,0,0);
          acc[j][ot] = __builtin_amdgcn_mfma_f32_16x16x32_bf16(twj, gf, acc[j][ot], 0,0,0);
        }
      }
    }
    // flush: rows = e_slot = quad*4+reg, cols o = oh*32 + ot*16 + lr
    #pragma unroll
    for (int j = 0; j < 4; ++j){
      int m = j0 + j;
      #pragma unroll
      for (int ot = 0; ot < 2; ++ot){
        int o = oh*32 + ot*16 + lr;
        float bb = bhl[m*66 + o];
        #pragma unroll
        for (int reg = 0; reg < 4; ++reg){
          int sl = quad*4 + reg;
          int eid = eidl[m][sl];
          if (eid < NE) msg[(size_t)posl[m][sl]*DD + o] = acc[j][ot][reg] + bb;
        }
      }
    }
  }
}

// ---------- per step: dst-major mean-reduce (contiguous stream) + BN partials
// 512 threads: 8 groups x 8 nodes for better latency hiding
__global__ __launch_bounds__(512) void k_red(const float* __restrict__ msg,
                      const int* __restrict__ rowp_d,
                      const float* __restrict__ invd, const float* __restrict__ cbias,
                      float* __restrict__ rst, float* __restrict__ part){
  __shared__ float ls[512], ls2[512];
  int t = threadIdx.x, blk = blockIdx.x;
  int o = t & 63, gg = t >> 6;
  float cb = cbias[o];
  float s = 0.f, s2 = 0.f;
  #pragma unroll 1
  for (int j = 0; j < 8; ++j){
    int n = blk*64 + gg*8 + j;
    if (n >= NN) break;
    int b = rowp_d[n], e = rowp_d[n+1];
    float a0 = 0.f, a1 = 0.f, a2 = 0.f, a3 = 0.f;
    int i = b;
    for (; i + 3 < e; i += 4){
      a0 += msg[(size_t)i*DD + o];
      a1 += msg[(size_t)(i+1)*DD + o];
      a2 += msg[(size_t)(i+2)*DD + o];
      a3 += msg[(size_t)(i+3)*DD + o];
    }
    for (; i < e; ++i) a0 += msg[(size_t)i*DD + o];
    float x = ((a0 + a1) + (a2 + a3)) * invd[n] + cb;
    rst[(size_t)n*DD + o] = x;
    s += x; s2 += x*x;
  }
  ls[t] = s; ls2[t] = s2;
  __syncthreads();
  if (t < 64){
    float a = 0.f;
    #pragma unroll
    for (int g = 0; g < 8; ++g) a += ls[g*64 + t];
    part[blk*128 + t] = a;
  } else if (t < 128){
    int o2 = t - 64;
    float a = 0.f;
    #pragma unroll
    for (int g = 0; g < 8; ++g) a += ls2[g*64 + o2];
    part[blk*128 + 64 + o2] = a;
  }
}

// ---------- per step: FUSED bnf + gru_pre + gru_gemm + gru_fin, gbuf-free.
// block = 64 nodes, 512 threads (8 waves), 1 block/CU (~150 KB LDS).
__global__ __launch_bounds__(512) void k_gru_one(
    const float* __restrict__ rst, const float* __restrict__ part,
    const float* __restrict__ gamma, const float* __restrict__ beta,
    ushort_t* __restrict__ ab, const ushort_t* __restrict__ wg,
    const float* __restrict__ bih, const float* __restrict__ bhh,
    float* __restrict__ hid, float* __restrict__ out, int write_out){
  __shared__ __align__(16) ushort_t As[64][136];   // 17.4 KB
  __shared__ __align__(16) ushort_t Bs[256][136];  // 69.6 KB
  __shared__ float gl[64*257];                     // 65.8 KB gates (pad 257)
  __shared__ float scl[64], sft[64];
  __shared__ float sh[128];
  int t = threadIdx.x;
  int r0 = blockIdx.x * 64;
  // BN final fold (ex-k_bnf), redundant per block
  if (t < 128){
    float s0 = 0.f, s1 = 0.f, s2 = 0.f, s3 = 0.f;
    int b = 0;
    for (; b + 3 < NRB; b += 4){
      s0 += part[b*128 + t];
      s1 += part[(b+1)*128 + t];
      s2 += part[(b+2)*128 + t];
      s3 += part[(b+3)*128 + t];
    }
    for (; b < NRB; ++b) s0 += part[b*128 + t];
    sh[t] = (s0 + s1) + (s2 + s3);
  }
  __syncthreads();
  if (t < 64){
    float mu = sh[t] / (float)NN;
    float var = sh[64+t] / (float)NN - mu*mu;
    if (var < 0.f) var = 0.f;
    float rsq = rsqrtf(var + 1e-5f);
    float sc = rsq * gamma[t];
    scl[t] = sc;
    sft[t] = beta[t] - mu*sc;
  }
  int wv = t >> 6, lane = t & 63;
  int lr = lane & 15, quad = lane >> 4;
  int n0 = wv * 32;                      // this wave's 32 output cols
  float4v acc[4][2];
  #pragma unroll
  for (int mt = 0; mt < 4; ++mt)
    #pragma unroll
    for (int nt = 0; nt < 2; ++nt) acc[mt][nt] = (float4v){0.f,0.f,0.f,0.f};
  for (int kt = 0; kt < 3; ++kt){
    __syncthreads();
    #pragma unroll
    for (int it = 0; it < 2; ++it){      // As: 64 rows x 16 chunks of 8
      int cid = t + it*512;
      int r = cid >> 4, ko = (cid & 15) * 8;
      int gm = r0 + r; if (gm >= NN) gm = NN-1;
      if (ko < 64){
        // m-part: compute from rst (kt 0,2: m_hi; kt 1: m_lo)
        float4 x0 = *(const float4*)(rst + (size_t)gm*DD + ko);
        float4 x1 = *(const float4*)(rst + (size_t)gm*DD + ko + 4);
        float xv[8] = {x0.x,x0.y,x0.z,x0.w,x1.x,x1.y,x1.z,x1.w};
        ushort_t u[8];
        #pragma unroll
        for (int jj = 0; jj < 8; ++jj){
          float m = fmaxf(xv[jj]*scl[ko+jj] + sft[ko+jj], 0.f);
          ushort_t mh = fsb(m);
          u[jj] = (kt == 1) ? fsb(m - bsf(mh)) : mh;
        }
        *(uint4*)&As[r][ko] = *(const uint4*)u;
      } else {
        // h-part from ab (kt0: h_hi@64, kt1: h_lo@192, kt2: h_hi@320)
        *(uint4*)&As[r][ko] = *(const uint4*)(ab + (size_t)gm*KAB + kt*128 + ko);
      }
    }
    #pragma unroll
    for (int it = 0; it < 8; ++it){      // Bs: 256 rows x 16 chunks of 8
      int cid = t + it*512;
      int rB = cid >> 4, ko = (cid & 15) * 8;
      *(uint4*)&Bs[rB][ko] = *(const uint4*)(wg + (size_t)rB*KAB + kt*128 + ko);
    }
    __syncthreads();
    #pragma unroll
    for (int ks = 0; ks < 4; ++ks){
      short8v a[4];
      #pragma unroll
      for (int mt = 0; mt < 4; ++mt)
        a[mt] = *(const short8v*)&As[mt*16 + lr][ks*32 + quad*8];
      #pragma unroll
      for (int nt = 0; nt < 2; ++nt){
        short8v b = *(const short8v*)&Bs[n0 + nt*16 + lr][ks*32 + quad*8];
        #pragma unroll
        for (int mt = 0; mt < 4; ++mt)
          acc[mt][nt] = __builtin_amdgcn_mfma_f32_16x16x32_bf16(a[mt], b, acc[mt][nt], 0,0,0);
      }
    }
  }
  // D -> gate LDS: row = mt*16 + quad*4 + reg, col = n0 + nt*16 + lr
  #pragma unroll
  for (int mt = 0; mt < 4; ++mt)
    #pragma unroll
    for (int nt = 0; nt < 2; ++nt){
      int col = n0 + nt*16 + lr;
      #pragma unroll
      for (int reg = 0; reg < 4; ++reg)
        gl[(mt*16 + quad*4 + reg)*257 + col] = acc[mt][nt][reg];
    }
  __syncthreads();
  // GRU nonlinearity + h update (ex-k_gru_fin), 64 rows x 64 o
  for (int idx = t; idx < 64*64; idx += 512){
    int row = idx >> 6, o = idx & 63;
    int v = r0 + row;
    if (v >= NN) break;
    const float* g = &gl[row*257];
    float aR  = g[o]       + bih[o]      + bhh[o];
    float aZ  = g[64 + o]  + bih[64+o]   + bhh[64+o];
    float aNi = g[128 + o] + bih[128+o];
    float aNh = g[192 + o] + bhh[128+o];
    float hprev = hid[(size_t)v*DD + o];
    float r = 1.f/(1.f+__expf(-aR));
    float z = 1.f/(1.f+__expf(-aZ));
    float n = tanhf(aNi + r*aNh);
    float hnew = (1.f - z)*n + z*hprev;
    hid[(size_t)v*DD + o] = hnew;
    ushort_t hh = fsb(hnew);
    float hl = hnew - bsf(hh);
    ab[(size_t)v*KAB + 64 + o]  = hh;
    ab[(size_t)v*KAB + 192 + o] = fsb(hl);
    ab[(size_t)v*KAB + 320 + o] = hh;
    if (write_out) out[(size_t)v*DD + o] = hnew;
  }
}

extern "C" void kernel_launch(void* const* d_in, const int* in_sizes, int n_in,
                              void* d_out, int out_size, void* d_ws, size_t ws_size,
                              hipStream_t stream){
  (void)out_size; (void)ws_size;
  float* out = (float*)d_out;

  // resolve input positions by size (== dict order on this instance)
  int p_nf=-1,p_ef=-1,p_src=-1,p_dst=-1,p_Wp=-1,p_bp=-1,p_W1=-1,p_b1=-1,
      p_W2=-1,p_b2=-1,p_cb=-1,p_gam=-1,p_bet=-1,p_Wih=-1,p_Whh=-1,p_bih=-1,p_bhh=-1;
  int c60000=0,c64=0,c12288=0,c192=0;
  for (int i = 0; i < n_in; ++i){
    switch (in_sizes[i]){
      case 1110000: p_nf = i; break;
      case 720000:  p_ef = i; break;
      case 60000:   if (c60000++ == 0) p_src = i; else p_dst = i; break;
      case 4736:    p_Wp = i; break;
      case 64:      { if (c64==0) p_bp=i; else if (c64==1) p_cb=i;
                      else if (c64==2) p_gam=i; else p_bet=i; c64++; } break;
      case 1536:    p_W1 = i; break;
      case 128:     p_b1 = i; break;
      case 524288:  p_W2 = i; break;
      case 4096:    p_b2 = i; break;
      case 12288:   if (c12288++ == 0) p_Wih = i; else p_Whh = i; break;
      case 192:    if (c192++ == 0) p_bih = i; else p_bhh = i; break;
      default: break;
    }
  }

  char* p = (char*)d_ws;
  auto alloc = [&](size_t bytes)->char*{
    char* r = p; p += (bytes + 255) & ~(size_t)255; return r;
  };
  int* flags = (int*)alloc(256);
  const int FPOS[15] = {p_nf,p_ef,p_Wp,p_bp,p_W1,p_b1,p_W2,p_b2,p_cb,p_gam,p_bet,
                        p_Wih,p_Whh,p_bih,p_bhh};
  CanonArgs ca;
  int maxn = 0;
  for (int j = 0; j < 15; ++j){
    int n = in_sizes[FPOS[j]];
    ca.in[j]  = d_in[FPOS[j]];
    ca.out[j] = (float*)alloc((size_t)n * 4);
    ca.n[j]   = n;
    if (n > maxn) maxn = n;
  }
  const float* nf  = ca.out[0];  const float* ef  = ca.out[1];
  const float* Wp  = ca.out[2];  const float* bp  = ca.out[3];
  const float* W1  = ca.out[4];  const float* b1  = ca.out[5];
  const float* W2  = ca.out[6];  const float* b2  = ca.out[7];
  const float* cb  = ca.out[8];  const float* gam = ca.out[9];
  const float* bet = ca.out[10]; const float* Wih = ca.out[11];
  const float* Whh = ca.out[12]; const float* bih = ca.out[13];
  const float* bhh = ca.out[14];
  int* srcc = (int*)alloc((size_t)NE*4);
  int* dstc = (int*)alloc((size_t)NE*4);

  ushort_t* thi   = (ushort_t*)alloc((size_t)(NE+1)*EH*2); // 15.4 MB
  ushort_t* tlo   = (ushort_t*)alloc((size_t)(NE+1)*EH*2); // 15.4 MB
  ushort_t* w2q   = (ushort_t*)alloc((size_t)NG*DD*2);     // 1.05 MB
  ushort_t* w2b   = (ushort_t*)alloc((size_t)DD*DD*2);     // 8 KB
  float* hid      = (float*)alloc((size_t)NN*DD*4);
  ushort_t* ab    = (ushort_t*)alloc((size_t)NN*KAB*2);    // 11.5 MB split activations
  ushort_t* wg    = (ushort_t*)alloc((size_t)256*KAB*2);   // 0.2 MB split GRU weights
  float* rst      = (float*)alloc((size_t)NN*DD*4);
  float* msg      = (float*)alloc((size_t)NE*DD*4);        // 15.4 MB per-edge messages
  float* part     = (float*)alloc((size_t)NRB*128*4);
  int* degall     = (int*)alloc((size_t)4*NN*4);
  int* deg  = degall;           // dst degrees
  int* curd = degall + NN;      // dst scatter cursor
  int* deg2 = degall + 2*NN; int* cursor2 = degall + 3*NN;
  float* invd = (float*)alloc((size_t)NN*4);
  int* rowp_d = (int*)alloc((size_t)(NN+1)*4);
  int* eidx_d = (int*)alloc((size_t)NE*4);
  int* epos   = (int*)alloc((size_t)NE*4);
  int* rowp2  = (int*)alloc((size_t)(NN+1)*4);
  float* invd2= (float*)alloc((size_t)NN*4);
  int* eidx2  = (int*)alloc((size_t)NE*4);
  int* tnode  = (int*)alloc((size_t)NTMAX*4);
  int* tbase  = (int*)alloc((size_t)NTMAX*4);
  int* tcnt   = (int*)alloc((size_t)NTMAX*4);
  int* ntb    = (int*)alloc(256);

  k_sniff<<<1, 256, 0, stream>>>((const ushort_t*)d_in[p_nf], (const int*)d_in[p_dst], flags);
  k_canon_all<<<dim3((maxn+255)/256, 15), 256, 0, stream>>>(ca, flags);
  k_canoni2<<<dim3((NE+255)/256, 2), 256, 0, stream>>>(d_in[p_src], d_in[p_dst],
                                                       srcc, dstc, flags);

  k_proj <<<NN/4,  256, 0, stream>>>(nf, Wp, bp, hid, ab);
  k_emlp <<<NE/2,  256, 0, stream>>>(ef, W1, b1, thi, tlo);
  k_zpad <<<1, 128, 0, stream>>>(thi, tlo);
  k_w2q  <<<(NG*DD + DD*DD + 255)/256, 256, 0, stream>>>(W2, b2, w2q, w2b);
  k_wgru <<<(256*KAB+255)/256, 256, 0, stream>>>(Wih, Whh, wg);
  k_zero <<<(4*NN+255)/256, 256, 0, stream>>>(degall, 4*NN);
  k_deg2 <<<dim3((NE+255)/256, 2), 256, 0, stream>>>(dstc, srcc, deg, deg2);
  k_scan2<<<2, 256, 0, stream>>>(deg, rowp_d, invd, deg2, rowp2, invd2);
  k_scatter2<<<dim3((NE+255)/256, 2), 256, 0, stream>>>(dstc, rowp_d, curd, eidx_d,
                                                        epos, srcc, rowp2, cursor2, eidx2);
  k_tiles<<<1, 256, 0, stream>>>(rowp2, tnode, tbase, tcnt, ntb);

  for (int s = 0; s < NSTEPS; ++s){
    k_fused7<<<NFB, 512, 0, stream>>>(ab, w2q, w2b, thi, tlo,
                                      tnode, tbase, tcnt, ntb, eidx2, epos, msg);
    k_red <<<NRB, 512, 0, stream>>>(msg, rowp_d, invd, cb, rst, part);
    k_gru_one<<<NGB, 512, 0, stream>>>(rst, part, gam, bet, ab, wg, bih, bhh,
                                       hid, out, (s == NSTEPS-1) ? 1 : 0);
  }
}